// Round 1
// baseline (161.276 us; speedup 1.0000x reference)
//
#include <hip/hip_runtime.h>

#define N 1024
#define F_IN 256
#define D_IN 128
#define D_OUT 64
#define KMAX 144   // max neighbors incl. self; degree ~ Binom(1023,0.0615): mean 63, max ~90. 144 = 10+ sigma.

// Kernel 1: wf[i,f] = sum_d ( sum_k nf[i,k]*lin_w[d,k] + lin_b[d] ) * weight[d,f]
__global__ __launch_bounds__(256) void wf_kernel(
    const float* __restrict__ nf, const float* __restrict__ lin_w,
    const float* __restrict__ lin_b, const float* __restrict__ weight,
    float* __restrict__ wf)
{
    __shared__ float nfs[F_IN];
    __shared__ float xs[D_IN];
    __shared__ float ps[256];
    const int i = blockIdx.x, t = threadIdx.x;

    nfs[t] = nf[(size_t)i * F_IN + t];
    __syncthreads();

    // x[d] = nf_row . lin_w_row_d + lin_b[d]; 2 threads per d (halves of k)
    {
        const int d = t & 127, h = t >> 7;
        const float* lw = lin_w + (size_t)d * F_IN + h * 128;
        const float* nn = nfs + h * 128;
        float a = 0.0f;
        #pragma unroll 8
        for (int k = 0; k < 128; ++k) a += nn[k] * lw[k];
        ps[t] = a;
    }
    __syncthreads();
    if (t < D_IN) xs[t] = ps[t] + ps[128 + t] + lin_b[t];
    __syncthreads();

    // wf[f] = x . weight[:,f]; 4 threads per f (quarters of d)
    {
        const int f = t & 63, q = t >> 6;
        float a = 0.0f;
        #pragma unroll 8
        for (int d = q * 32; d < q * 32 + 32; ++d) a += xs[d] * weight[d * D_OUT + f];
        ps[t] = a;
    }
    __syncthreads();
    if (t < D_OUT)
        wf[(size_t)i * D_OUT + t] = ps[t] + ps[64 + t] + ps[128 + t] + ps[192 + t];
}

// Kernel 2: out[i,f] = 2 * sum_{b<j in nbr(i)} sib[b,j]*wf[b,f]*wf[j,f] / nc[i]^2
// (sib is exactly symmetric with zero diagonal)
__global__ __launch_bounds__(256) void pair_kernel(
    const float* __restrict__ A, const float* __restrict__ sib,
    const float* __restrict__ nc, const float* __restrict__ wf,
    float* __restrict__ out)
{
    __shared__ float wf_s[KMAX * D_OUT];
    __shared__ int   nbr[KMAX];
    __shared__ int   cnt;
    __shared__ float red[4 * D_OUT];

    const int i = blockIdx.x, t = threadIdx.x;
    if (t == 0) cnt = 0;
    __syncthreads();

    // Phase A: neighbor list from adjacency row (values are exactly 0.0/1.0)
    const float* arow = A + (size_t)i * N;
    for (int j = t; j < N; j += 256) {
        if (arow[j] != 0.0f) {
            int p = atomicAdd(&cnt, 1);
            if (p < KMAX) nbr[p] = j;
        }
    }
    __syncthreads();
    int K = cnt; if (K > KMAX) K = KMAX;

    // Phase B: stage wf rows of neighbors into LDS (coalesced per row)
    for (int idx = t; idx < K * D_OUT; idx += 256) {
        wf_s[idx] = wf[(size_t)nbr[idx >> 6] * D_OUT + (idx & 63)];
    }
    __syncthreads();

    // Phase C: triangular pair accumulation. wave w handles rows bi = w, w+4, ...
    const int wave = t >> 6, lane = t & 63;
    float acc = 0.0f;
    for (int bi = wave; bi < K; bi += 4) {
        const float* srow = sib + (size_t)nbr[bi] * N;
        const float  wb   = wf_s[bi * D_OUT + lane];
        #pragma unroll 4
        for (int j = bi + 1; j < K; ++j) {
            const float s  = srow[nbr[j]];          // wave-uniform broadcast, L2-hot
            const float wj = wf_s[j * D_OUT + lane];
            acc += (s * wb) * wj;
        }
    }
    red[wave * D_OUT + lane] = acc;
    __syncthreads();

    if (t < D_OUT) {
        const float v = red[t] + red[64 + t] + red[128 + t] + red[192 + t];
        const float c = nc[i];
        out[(size_t)i * D_OUT + t] = 2.0f * v / (c * c);
    }
}

extern "C" void kernel_launch(void* const* d_in, const int* in_sizes, int n_in,
                              void* d_out, int out_size, void* d_ws, size_t ws_size,
                              hipStream_t stream) {
    const float* nf     = (const float*)d_in[0];  // (N, F_IN)
    const float* A      = (const float*)d_in[1];  // (N, N)
    // d_in[2] = mask_father == A[:,None,:], redundant
    const float* nc     = (const float*)d_in[3];  // (N, 1)
    const float* sib    = (const float*)d_in[4];  // mask_hadamard (N, N)
    const float* lin_w  = (const float*)d_in[5];  // (D_IN, F_IN)
    const float* lin_b  = (const float*)d_in[6];  // (D_IN,)
    const float* weight = (const float*)d_in[7];  // (D_IN, D_OUT)
    float*       out    = (float*)d_out;          // (N, D_OUT)
    float*       wf     = (float*)d_ws;           // (N, D_OUT) scratch, 256 KB

    wf_kernel<<<N, 256, 0, stream>>>(nf, lin_w, lin_b, weight, wf);
    pair_kernel<<<N, 256, 0, stream>>>(A, sib, nc, wf, out);
}

// Round 2
// 127.173 us; speedup vs baseline: 1.2682x; 1.2682x over previous
//
#include <hip/hip_runtime.h>

#define N 1024
#define F_IN 256
#define D_IN 128
#define D_OUT 64
#define KMAX 128   // max neighbors incl. self; degree ~ Binom(1023,0.0615): mean 63, sd 7.7; 128 = 8+ sigma

// ---------------------------------------------------------------------------
// Kernel 0: W2[k,f] = sum_d lin_w[d,k] * weight[d,f]   (256 x 64)
//           b2[f]   = sum_d lin_b[d]   * weight[d,f]
// wf = (nf @ lin_w^T + lin_b) @ weight  ==  nf @ W2 + b2
// ---------------------------------------------------------------------------
__global__ __launch_bounds__(256) void w2_kernel(
    const float* __restrict__ lin_w, const float* __restrict__ lin_b,
    const float* __restrict__ weight, float* __restrict__ W2,
    float* __restrict__ b2)
{
    const int t = threadIdx.x;
    if (blockIdx.x < 64) {
        const int k = blockIdx.x * 4 + (t >> 6);   // wave-uniform
        const int f = t & 63;
        float acc = 0.0f;
        #pragma unroll 4
        for (int d = 0; d < D_IN; ++d)
            acc += lin_w[d * F_IN + k] * weight[d * D_OUT + f];
        W2[k * D_OUT + f] = acc;
    } else if (t < D_OUT) {
        float acc = 0.0f;
        #pragma unroll 4
        for (int d = 0; d < D_IN; ++d)
            acc += lin_b[d] * weight[d * D_OUT + t];
        b2[t] = acc;
    }
}

// ---------------------------------------------------------------------------
// Kernel 1: wf[i,f] = b2[f] + sum_k nf[i,k] * W2[k,f]
// One wave per row i; lane = f. nf reads are wave-uniform float4 broadcasts,
// W2 reads are coalesced 256B/wave and L1/L2-hot.
// ---------------------------------------------------------------------------
__global__ __launch_bounds__(256) void wf2_kernel(
    const float* __restrict__ nf, const float* __restrict__ W2,
    const float* __restrict__ b2, float* __restrict__ wf)
{
    const int t = threadIdx.x;
    const int i = blockIdx.x * 4 + (t >> 6);
    const int f = t & 63;
    const float4* nf4 = (const float4*)(nf + (size_t)i * F_IN);
    float acc = b2[f];
    #pragma unroll 4
    for (int kk = 0; kk < F_IN / 4; ++kk) {
        const float4 v = nf4[kk];
        const float* w = W2 + kk * 4 * D_OUT + f;
        acc += v.x * w[0] + v.y * w[D_OUT] + v.z * w[2 * D_OUT] + v.w * w[3 * D_OUT];
    }
    wf[(size_t)i * D_OUT + f] = acc;
}

// ---------------------------------------------------------------------------
// Kernel 2: out[i,f] = 2 * sum_{b<j in nbr(i)} sib[b,j]*wf[b,f]*wf[j,f] / nc[i]^2
// One 1024-thread block per node. sib submatrix (small exact ints <= ~91)
// pre-gathered into LDS as uint8 with full memory-level parallelism; pair
// loop then runs entirely out of LDS.
// ---------------------------------------------------------------------------
__global__ __launch_bounds__(1024, 8) void pair_kernel(
    const float* __restrict__ A, const float* __restrict__ sib,
    const float* __restrict__ nc, const float* __restrict__ wf,
    float* __restrict__ out)
{
    __shared__ float         wf_s[KMAX * D_OUT];     // 32 KB
    __shared__ unsigned char sib_s[KMAX * KMAX];     // 16 KB
    __shared__ int           nbr[KMAX];
    __shared__ int           cnt;
    __shared__ float         red[16 * D_OUT];        // 4 KB

    const int i = blockIdx.x, t = threadIdx.x;
    const int wave = t >> 6, lane = t & 63;
    if (t == 0) cnt = 0;
    __syncthreads();

    // Phase A: neighbor list from adjacency row (values exactly 0.0/1.0)
    {
        const float a = A[(size_t)i * N + t];
        if (a != 0.0f) {
            int p = atomicAdd(&cnt, 1);
            if (p < KMAX) nbr[p] = t;
        }
    }
    __syncthreads();
    int K = cnt; if (K > KMAX) K = KMAX;

    // Phase B1: stage wf rows of neighbors (float4-coalesced)
    for (int idx = t; idx < K * (D_OUT / 4); idx += 1024)
        ((float4*)wf_s)[idx] = ((const float4*)wf)[nbr[idx >> 4] * (D_OUT / 4) + (idx & 15)];

    // Phase B2: gather sib submatrix -> LDS uint8 (values are exact small ints)
    for (int bi = wave; bi < K; bi += 16) {
        const float* srow = sib + (size_t)nbr[bi] * N;
        for (int j = lane; j < K; j += 64)
            sib_s[bi * KMAX + j] = (unsigned char)(srow[nbr[j]] + 0.5f);
    }
    __syncthreads();

    // Phase C: triangular pair accumulation, all from LDS
    float acc = 0.0f;
    for (int bi = wave; bi < K; bi += 16) {
        const float wb = wf_s[bi * D_OUT + lane];
        const unsigned char* sr = sib_s + bi * KMAX;
        #pragma unroll 4
        for (int j = bi + 1; j < K; ++j) {
            acc += (float)sr[j] * wb * wf_s[j * D_OUT + lane];
        }
    }
    red[wave * D_OUT + lane] = acc;
    __syncthreads();

    if (t < D_OUT) {
        float v = 0.0f;
        #pragma unroll
        for (int w = 0; w < 16; ++w) v += red[w * D_OUT + t];
        const float c = nc[i];
        out[(size_t)i * D_OUT + t] = 2.0f * v / (c * c);
    }
}

extern "C" void kernel_launch(void* const* d_in, const int* in_sizes, int n_in,
                              void* d_out, int out_size, void* d_ws, size_t ws_size,
                              hipStream_t stream) {
    const float* nf     = (const float*)d_in[0];  // (N, F_IN)
    const float* A      = (const float*)d_in[1];  // (N, N)
    // d_in[2] = mask_father == A[:,None,:], redundant
    const float* nc     = (const float*)d_in[3];  // (N, 1)
    const float* sib    = (const float*)d_in[4];  // mask_hadamard (N, N)
    const float* lin_w  = (const float*)d_in[5];  // (D_IN, F_IN)
    const float* lin_b  = (const float*)d_in[6];  // (D_IN,)
    const float* weight = (const float*)d_in[7];  // (D_IN, D_OUT)
    float*       out    = (float*)d_out;          // (N, D_OUT)

    float* wf = (float*)d_ws;                     // N*D_OUT   = 256 KB
    float* W2 = wf + (size_t)N * D_OUT;           // F_IN*D_OUT = 64 KB
    float* b2 = W2 + (size_t)F_IN * D_OUT;        // 256 B

    w2_kernel <<<65,  256,  0, stream>>>(lin_w, lin_b, weight, W2, b2);
    wf2_kernel<<<N/4, 256,  0, stream>>>(nf, W2, b2, wf);
    pair_kernel<<<N,  1024, 0, stream>>>(A, sib, nc, wf, out);
}

// Round 3
// 118.944 us; speedup vs baseline: 1.3559x; 1.0692x over previous
//
#include <hip/hip_runtime.h>

#define N 1024
#define F_IN 256
#define D_IN 128
#define D_OUT 64
#define KMAX 128   // actual max neighbors incl. self ~93 (verified: KMAX=128 passed R2)

// ---------------------------------------------------------------------------
// prep: block i: (a) sib row f32 -> uint8 (values are exact small ints),
//                (b) ballot-compact A row -> sorted u16 neighbor list + count
// ---------------------------------------------------------------------------
__global__ __launch_bounds__(256) void prep_kernel(
    const float* __restrict__ A, const float* __restrict__ sib,
    unsigned char* __restrict__ sib8, unsigned short* __restrict__ nbrg,
    int* __restrict__ cntg)
{
    const int i = blockIdx.x, t = threadIdx.x;
    const int lane = t & 63, wave = t >> 6;

    // (a) sib8 conversion: 1024 floats via float4 -> uchar4, coalesced
    {
        const float4 v = ((const float4*)(sib + (size_t)i * N))[t];
        uchar4 u;
        u.x = (unsigned char)(v.x + 0.5f);
        u.y = (unsigned char)(v.y + 0.5f);
        u.z = (unsigned char)(v.z + 0.5f);
        u.w = (unsigned char)(v.w + 0.5f);
        ((uchar4*)(sib8 + (size_t)i * N))[t] = u;
    }

    // (b) ordered stream compaction over 4 chunks of 256 columns
    __shared__ int woff[4];
    __shared__ int base;
    if (t == 0) base = 0;
    const float* arow = A + (size_t)i * N;
    for (int c = 0; c < 4; ++c) {
        __syncthreads();
        const int j = c * 256 + t;
        const float a = arow[j];
        const unsigned long long m = __ballot(a != 0.0f);
        if (lane == 0) woff[wave] = __popcll(m);
        __syncthreads();
        int off = base;
        for (int w = 0; w < wave; ++w) off += woff[w];
        const int pos = off + __popcll(m & ((1ULL << lane) - 1ULL));
        if (a != 0.0f && pos < KMAX) nbrg[(size_t)i * KMAX + pos] = (unsigned short)j;
        __syncthreads();
        if (t == 0) base += woff[0] + woff[1] + woff[2] + woff[3];
    }
    __syncthreads();
    if (t == 0) cntg[i] = base < KMAX ? base : KMAX;
}

// ---------------------------------------------------------------------------
// W2[k,f] = sum_d lin_w[d,k]*weight[d,f]; b2[f] = sum_d lin_b[d]*weight[d,f]
// wf = (nf @ lin_w^T + lin_b) @ weight == nf @ W2 + b2
// ---------------------------------------------------------------------------
__global__ __launch_bounds__(256) void w2_kernel(
    const float* __restrict__ lin_w, const float* __restrict__ lin_b,
    const float* __restrict__ weight, float* __restrict__ W2,
    float* __restrict__ b2)
{
    const int t = threadIdx.x;
    if (blockIdx.x < 64) {
        const int k = blockIdx.x * 4 + (t >> 6);   // wave-uniform
        const int f = t & 63;
        float acc = 0.0f;
        #pragma unroll 4
        for (int d = 0; d < D_IN; ++d)
            acc += lin_w[d * F_IN + k] * weight[d * D_OUT + f];
        W2[k * D_OUT + f] = acc;
    } else if (t < D_OUT) {
        float acc = 0.0f;
        #pragma unroll 4
        for (int d = 0; d < D_IN; ++d)
            acc += lin_b[d] * weight[d * D_OUT + t];
        b2[t] = acc;
    }
}

// ---------------------------------------------------------------------------
// wf[i,f] = b2[f] + sum_k nf[i,k]*W2[k,f]; 2 waves per row (k split in half)
// for 2x the wave parallelism of the R2 version. Grid = N/2 blocks.
// ---------------------------------------------------------------------------
__global__ __launch_bounds__(256) void wf2_kernel(
    const float* __restrict__ nf, const float* __restrict__ W2,
    const float* __restrict__ b2, float* __restrict__ wf)
{
    __shared__ float red[4 * D_OUT];
    const int t = threadIdx.x, lane = t & 63, wave = t >> 6;
    const int row = blockIdx.x * 2 + (wave >> 1);
    const int half = wave & 1;
    const float4* nf4 = (const float4*)(nf + (size_t)row * F_IN);
    float acc = half ? 0.0f : b2[lane];
    #pragma unroll 8
    for (int kk = half * 32; kk < half * 32 + 32; ++kk) {
        const float4 v = nf4[kk];
        const float* w = W2 + kk * 4 * D_OUT + lane;
        acc += v.x * w[0] + v.y * w[D_OUT] + v.z * w[2 * D_OUT] + v.w * w[3 * D_OUT];
    }
    red[wave * D_OUT + lane] = acc;
    __syncthreads();
    if (t < 128) {
        const int rr = t >> 6, f = t & 63;
        wf[(size_t)(blockIdx.x * 2 + rr) * D_OUT + f] =
            red[(rr * 2) * D_OUT + f] + red[(rr * 2 + 1) * D_OUT + f];
    }
}

// ---------------------------------------------------------------------------
// out[i,f] = 2 * sum_{b<j in nbr(i)} sib[b,j]*wf[b,f]*wf[j,f] / nc[i]^2
// 1024 threads/block, one block per node. sib gathered from L2-hot uint8
// matrix; pair loop: lane = (f4, p) with p parallelizing 4 j's per step,
// float4 LDS reads, shfl_xor p-reduction.
// ---------------------------------------------------------------------------
__global__ __launch_bounds__(1024, 8) void pair2_kernel(
    const unsigned char* __restrict__ sib8, const unsigned short* __restrict__ nbrg,
    const int* __restrict__ cntg, const float* __restrict__ nc,
    const float* __restrict__ wf, float* __restrict__ out)
{
    __shared__ float          wf_s[(KMAX + 4) * D_OUT];   // 33 KB (+4 zero pad rows)
    __shared__ unsigned char  sib_s[KMAX * KMAX];         // 16 KB
    __shared__ unsigned short nbr[KMAX];
    __shared__ float          red[16 * D_OUT];            // 4 KB

    const int i = blockIdx.x, t = threadIdx.x;
    const int wave = t >> 6, lane = t & 63;
    int K = cntg[i]; if (K > 124) K = 124;   // actual max ~93; keeps j=j0+p in-bounds

    // zero sib_s (16 KB) so padded j-tail reads give s=0
    ((int*)sib_s)[t]        = 0;
    ((int*)sib_s)[t + 1024] = 0;
    ((int*)sib_s)[t + 2048] = 0;
    ((int*)sib_s)[t + 3072] = 0;
    // zero wf_s pad rows [K, K+4) so s=0 never multiplies garbage/NaN
    if (t < 256) wf_s[K * D_OUT + t] = 0.0f;
    if (t < KMAX) nbr[t] = nbrg[(size_t)i * KMAX + t];
    __syncthreads();

    // stage wf rows of neighbors (float4, coalesced per row)
    for (int idx = t; idx < K * (D_OUT / 4); idx += 1024)
        ((float4*)wf_s)[idx] =
            ((const float4*)wf)[(int)nbr[idx >> 4] * (D_OUT / 4) + (idx & 15)];
    // gather K x K sib submatrix from uint8 (L2-hot, 1 MB), high MLP
    for (int idx = t; idx < K * KMAX; idx += 1024) {
        const int bi = idx >> 7, j = idx & (KMAX - 1);
        if (j < K) sib_s[idx] = sib8[(size_t)nbr[bi] * N + nbr[j]];
    }
    __syncthreads();

    // triangular pair loop: wave handles rows bi = wave, wave+16, ...
    const int f4 = (lane & 15) * 4, p = lane >> 4;
    float4 acc = make_float4(0.f, 0.f, 0.f, 0.f);
    for (int bi = wave; bi < K; bi += 16) {
        const float4 wb = *(const float4*)&wf_s[bi * D_OUT + f4];
        const unsigned char* sr = sib_s + bi * KMAX;
        for (int j0 = bi + 1; j0 < K; j0 += 4) {
            const int j = j0 + p;                  // may reach K+2: sib=0 pad
            const float s = (float)sr[j];
            const float4 wj = *(const float4*)&wf_s[j * D_OUT + f4];
            acc.x += s * (wb.x * wj.x);
            acc.y += s * (wb.y * wj.y);
            acc.z += s * (wb.z * wj.z);
            acc.w += s * (wb.w * wj.w);
        }
    }
    // reduce over p (lane bits 4,5) via shuffle butterfly
    #pragma unroll
    for (int m = 16; m <= 32; m += m) {
        acc.x += __shfl_xor(acc.x, m, 64);
        acc.y += __shfl_xor(acc.y, m, 64);
        acc.z += __shfl_xor(acc.z, m, 64);
        acc.w += __shfl_xor(acc.w, m, 64);
    }
    if (p == 0) *(float4*)&red[wave * D_OUT + f4] = acc;
    __syncthreads();

    if (t < D_OUT) {
        float v = 0.f;
        #pragma unroll
        for (int w = 0; w < 16; ++w) v += red[w * D_OUT + t];
        const float c = nc[i];
        out[(size_t)i * D_OUT + t] = 2.0f * v / (c * c);
    }
}

extern "C" void kernel_launch(void* const* d_in, const int* in_sizes, int n_in,
                              void* d_out, int out_size, void* d_ws, size_t ws_size,
                              hipStream_t stream) {
    const float* nf     = (const float*)d_in[0];  // (N, F_IN)
    const float* A      = (const float*)d_in[1];  // (N, N)
    // d_in[2] = mask_father == A[:,None,:], redundant
    const float* nc     = (const float*)d_in[3];  // (N, 1)
    const float* sib    = (const float*)d_in[4];  // mask_hadamard (N, N)
    const float* lin_w  = (const float*)d_in[5];  // (D_IN, F_IN)
    const float* lin_b  = (const float*)d_in[6];  // (D_IN,)
    const float* weight = (const float*)d_in[7];  // (D_IN, D_OUT)
    float*       out    = (float*)d_out;          // (N, D_OUT)

    char* ws = (char*)d_ws;
    float*          wf    = (float*)(ws);                       // 256 KB
    float*          W2    = (float*)(ws + 262144);              // 64 KB
    float*          b2    = (float*)(ws + 327680);              // 1 KB (padded)
    unsigned char*  sib8  = (unsigned char*)(ws + 328704);      // 1 MB
    unsigned short* nbr16 = (unsigned short*)(ws + 1377280);    // 256 KB
    int*            cnt   = (int*)(ws + 1639424);               // 4 KB

    prep_kernel<<<N,   256,  0, stream>>>(A, sib, sib8, nbr16, cnt);
    w2_kernel  <<<65,  256,  0, stream>>>(lin_w, lin_b, weight, W2, b2);
    wf2_kernel <<<N/2, 256,  0, stream>>>(nf, W2, b2, wf);
    pair2_kernel<<<N,  1024, 0, stream>>>(sib8, nbr16, cnt, nc, wf, out);
}

// Round 4
// 113.433 us; speedup vs baseline: 1.4218x; 1.0486x over previous
//
#include <hip/hip_runtime.h>

#define N 1024
#define F_IN 256
#define D_IN 128
#define D_OUT 64
#define KMAX 128   // actual max neighbors incl. self ~93 (KMAX=128 verified passing R2/R3)

// ---------------------------------------------------------------------------
// Fused prep + w2. Blocks 0..N-1: per-node prep (sib row f32->uint8, ballot-
// compact A row -> sorted u16 neighbor list + count). Blocks N..N+64: W2/b2.
//   W2[k,f] = sum_d lin_w[d,k]*weight[d,f];  b2[f] = sum_d lin_b[d]*weight[d,f]
//   (wf = (nf @ lin_w^T + lin_b) @ weight == nf @ W2 + b2)
// ---------------------------------------------------------------------------
__global__ __launch_bounds__(256) void prep_w2_kernel(
    const float* __restrict__ A, const float* __restrict__ sib,
    const float* __restrict__ lin_w, const float* __restrict__ lin_b,
    const float* __restrict__ weight,
    unsigned char* __restrict__ sib8, unsigned short* __restrict__ nbrg,
    int* __restrict__ cntg, float* __restrict__ W2, float* __restrict__ b2)
{
    const int t = threadIdx.x;
    if (blockIdx.x >= N) {
        const int blk = blockIdx.x - N;
        if (blk < 64) {
            const int k = blk * 4 + (t >> 6);   // wave-uniform
            const int f = t & 63;
            float acc = 0.0f;
            #pragma unroll 4
            for (int d = 0; d < D_IN; ++d)
                acc += lin_w[d * F_IN + k] * weight[d * D_OUT + f];
            W2[k * D_OUT + f] = acc;
        } else if (t < D_OUT) {
            float acc = 0.0f;
            #pragma unroll 4
            for (int d = 0; d < D_IN; ++d)
                acc += lin_b[d] * weight[d * D_OUT + t];
            b2[t] = acc;
        }
        return;
    }

    const int i = blockIdx.x;
    const int lane = t & 63, wave = t >> 6;

    // (a) sib8 conversion: 1024 floats via float4 -> uchar4, coalesced
    {
        const float4 v = ((const float4*)(sib + (size_t)i * N))[t];
        uchar4 u;
        u.x = (unsigned char)(v.x + 0.5f);
        u.y = (unsigned char)(v.y + 0.5f);
        u.z = (unsigned char)(v.z + 0.5f);
        u.w = (unsigned char)(v.w + 0.5f);
        ((uchar4*)(sib8 + (size_t)i * N))[t] = u;
    }

    // (b) ordered stream compaction over 4 chunks of 256 columns
    __shared__ int woff[4];
    __shared__ int base;
    if (t == 0) base = 0;
    const float* arow = A + (size_t)i * N;
    for (int c = 0; c < 4; ++c) {
        __syncthreads();
        const int j = c * 256 + t;
        const float a = arow[j];
        const unsigned long long m = __ballot(a != 0.0f);
        if (lane == 0) woff[wave] = __popcll(m);
        __syncthreads();
        int off = base;
        for (int w = 0; w < wave; ++w) off += woff[w];
        const int pos = off + __popcll(m & ((1ULL << lane) - 1ULL));
        if (a != 0.0f && pos < KMAX) nbrg[(size_t)i * KMAX + pos] = (unsigned short)j;
        __syncthreads();
        if (t == 0) base += woff[0] + woff[1] + woff[2] + woff[3];
    }
    __syncthreads();
    if (t == 0) cntg[i] = base < KMAX ? base : KMAX;
}

// ---------------------------------------------------------------------------
// wf[i,f] = b2[f] + sum_k nf[i,k]*W2[k,f]; 2 waves per row (k split in half).
// ---------------------------------------------------------------------------
__global__ __launch_bounds__(256) void wf2_kernel(
    const float* __restrict__ nf, const float* __restrict__ W2,
    const float* __restrict__ b2, float* __restrict__ wf)
{
    __shared__ float red[4 * D_OUT];
    const int t = threadIdx.x, lane = t & 63, wave = t >> 6;
    const int row = blockIdx.x * 2 + (wave >> 1);
    const int half = wave & 1;
    const float4* nf4 = (const float4*)(nf + (size_t)row * F_IN);
    float acc = half ? 0.0f : b2[lane];
    #pragma unroll 8
    for (int kk = half * 32; kk < half * 32 + 32; ++kk) {
        const float4 v = nf4[kk];
        const float* w = W2 + kk * 4 * D_OUT + lane;
        acc += v.x * w[0] + v.y * w[D_OUT] + v.z * w[2 * D_OUT] + v.w * w[3 * D_OUT];
    }
    red[wave * D_OUT + lane] = acc;
    __syncthreads();
    if (t < 128) {
        const int rr = t >> 6, f = t & 63;
        wf[(size_t)(blockIdx.x * 2 + rr) * D_OUT + f] =
            red[(rr * 2) * D_OUT + f] + red[(rr * 2 + 1) * D_OUT + f];
    }
}

// ---------------------------------------------------------------------------
// out[i,f] = 2 * sum_{b<j in nbr(i)} sib[b,j]*wf[b,f]*wf[j,f] / nc[i]^2
// 1024 threads/block, one block per node. Upper-triangle-only sib gather
// (halves scattered L2 loads); pad columns [K,K+4) zeroed instead of the
// full 16 KB clear. Pair loop: lane=(f4,p), p parallelizes 4 j's/step,
// float4 LDS reads, shfl_xor p-reduction.
// ---------------------------------------------------------------------------
__global__ __launch_bounds__(1024, 8) void pair2_kernel(
    const unsigned char* __restrict__ sib8, const unsigned short* __restrict__ nbrg,
    const int* __restrict__ cntg, const float* __restrict__ nc,
    const float* __restrict__ wf, float* __restrict__ out)
{
    __shared__ float          wf_s[(KMAX + 4) * D_OUT];   // 33 KB (+4 pad rows)
    __shared__ unsigned char  sib_s[KMAX * KMAX];         // 16 KB
    __shared__ unsigned short nbr[KMAX];
    __shared__ float          red[16 * D_OUT];            // 4 KB

    const int i = blockIdx.x, t = threadIdx.x;
    const int wave = t >> 6, lane = t & 63;
    int K = cntg[i]; if (K > 124) K = 124;   // actual max ~93; keeps j=j0+p in-bounds

    // zero only what the pair loop can touch out-of-range:
    // sib columns [K, K+4) of every row, and wf_s rows [K, K+4).
    if (t < 512) {
        const int bi = t >> 2;
        sib_s[bi * KMAX + K + (t & 3)] = 0;
    } else if (t < 768) {
        wf_s[K * D_OUT + (t - 512)] = 0.0f;
    }
    if (t < KMAX) nbr[t] = nbrg[(size_t)i * KMAX + t];
    __syncthreads();

    // stage wf rows of neighbors (float4, coalesced per row)
    for (int idx = t; idx < K * (D_OUT / 4); idx += 1024)
        ((float4*)wf_s)[idx] =
            ((const float4*)wf)[(int)nbr[idx >> 4] * (D_OUT / 4) + (idx & 15)];
    // gather upper triangle of K x K sib submatrix from uint8 (L2-hot, 1 MB)
    for (int idx = t; idx < K * KMAX; idx += 1024) {
        const int bi = idx >> 7, j = idx & (KMAX - 1);
        if (j > bi && j < K) sib_s[idx] = sib8[(size_t)nbr[bi] * N + nbr[j]];
    }
    __syncthreads();

    // triangular pair loop: wave handles rows bi = wave, wave+16, ...
    const int f4 = (lane & 15) * 4, p = lane >> 4;
    float4 acc = make_float4(0.f, 0.f, 0.f, 0.f);
    for (int bi = wave; bi < K; bi += 16) {
        const float4 wb = *(const float4*)&wf_s[bi * D_OUT + f4];
        const unsigned char* sr = sib_s + bi * KMAX;
        for (int j0 = bi + 1; j0 < K; j0 += 4) {
            const int j = j0 + p;                  // may reach K+2: sib pad = 0
            const float s = (float)sr[j];
            const float4 wj = *(const float4*)&wf_s[j * D_OUT + f4];
            acc.x += s * (wb.x * wj.x);
            acc.y += s * (wb.y * wj.y);
            acc.z += s * (wb.z * wj.z);
            acc.w += s * (wb.w * wj.w);
        }
    }
    // reduce over p (lane bits 4,5) via shuffle butterfly
    #pragma unroll
    for (int m = 16; m <= 32; m += m) {
        acc.x += __shfl_xor(acc.x, m, 64);
        acc.y += __shfl_xor(acc.y, m, 64);
        acc.z += __shfl_xor(acc.z, m, 64);
        acc.w += __shfl_xor(acc.w, m, 64);
    }
    if (p == 0) *(float4*)&red[wave * D_OUT + f4] = acc;
    __syncthreads();

    if (t < D_OUT) {
        float v = 0.f;
        #pragma unroll
        for (int w = 0; w < 16; ++w) v += red[w * D_OUT + t];
        const float c = nc[i];
        out[(size_t)i * D_OUT + t] = 2.0f * v / (c * c);
    }
}

extern "C" void kernel_launch(void* const* d_in, const int* in_sizes, int n_in,
                              void* d_out, int out_size, void* d_ws, size_t ws_size,
                              hipStream_t stream) {
    const float* nf     = (const float*)d_in[0];  // (N, F_IN)
    const float* A      = (const float*)d_in[1];  // (N, N)
    // d_in[2] = mask_father == A[:,None,:], redundant
    const float* nc     = (const float*)d_in[3];  // (N, 1)
    const float* sib    = (const float*)d_in[4];  // mask_hadamard (N, N)
    const float* lin_w  = (const float*)d_in[5];  // (D_IN, F_IN)
    const float* lin_b  = (const float*)d_in[6];  // (D_IN,)
    const float* weight = (const float*)d_in[7];  // (D_IN, D_OUT)
    float*       out    = (float*)d_out;          // (N, D_OUT)

    char* ws = (char*)d_ws;
    float*          wf    = (float*)(ws);                       // 256 KB
    float*          W2    = (float*)(ws + 262144);              // 64 KB
    float*          b2    = (float*)(ws + 327680);              // 1 KB (padded)
    unsigned char*  sib8  = (unsigned char*)(ws + 328704);      // 1 MB
    unsigned short* nbr16 = (unsigned short*)(ws + 1377280);    // 256 KB
    int*            cnt   = (int*)(ws + 1639424);               // 4 KB

    prep_w2_kernel<<<N + 65, 256,  0, stream>>>(A, sib, lin_w, lin_b, weight,
                                                sib8, nbr16, cnt, W2, b2);
    wf2_kernel    <<<N / 2,  256,  0, stream>>>(nf, W2, b2, wf);
    pair2_kernel  <<<N,      1024, 0, stream>>>(sib8, nbr16, cnt, nc, wf, out);
}

// Round 5
// 106.855 us; speedup vs baseline: 1.5093x; 1.0616x over previous
//
#include <hip/hip_runtime.h>

#define N 1024
#define F_IN 256
#define D_IN 128
#define D_OUT 64
#define KMAX 128     // actual max neighbors incl. self ~93 (KMAX=128 verified R2-R4)
#define SROW 132     // sib_sT row stride in bytes (128 + 4 pad: debanks p-stride reads)

// ---------------------------------------------------------------------------
// Fused prep + w2. Blocks 0..N-1: per-node prep (sib row f32->uint8, ballot-
// compact A row -> sorted u16 neighbor list + count). Blocks N..N+64: W2/b2.
//   W2[k,f] = sum_d lin_w[d,k]*weight[d,f];  b2[f] = sum_d lin_b[d]*weight[d,f]
//   (wf = (nf @ lin_w^T + lin_b) @ weight == nf @ W2 + b2)
// ---------------------------------------------------------------------------
__global__ __launch_bounds__(256) void prep_w2_kernel(
    const float* __restrict__ A, const float* __restrict__ sib,
    const float* __restrict__ lin_w, const float* __restrict__ lin_b,
    const float* __restrict__ weight,
    unsigned char* __restrict__ sib8, unsigned short* __restrict__ nbrg,
    int* __restrict__ cntg, float* __restrict__ W2, float* __restrict__ b2)
{
    const int t = threadIdx.x;
    if (blockIdx.x >= N) {
        const int blk = blockIdx.x - N;
        if (blk < 64) {
            const int k = blk * 4 + (t >> 6);   // wave-uniform
            const int f = t & 63;
            float acc = 0.0f;
            #pragma unroll 4
            for (int d = 0; d < D_IN; ++d)
                acc += lin_w[d * F_IN + k] * weight[d * D_OUT + f];
            W2[k * D_OUT + f] = acc;
        } else if (t < D_OUT) {
            float acc = 0.0f;
            #pragma unroll 4
            for (int d = 0; d < D_IN; ++d)
                acc += lin_b[d] * weight[d * D_OUT + t];
            b2[t] = acc;
        }
        return;
    }

    const int i = blockIdx.x;
    const int lane = t & 63, wave = t >> 6;

    // (a) sib8 conversion: 1024 floats via float4 -> uchar4, coalesced
    {
        const float4 v = ((const float4*)(sib + (size_t)i * N))[t];
        uchar4 u;
        u.x = (unsigned char)(v.x + 0.5f);
        u.y = (unsigned char)(v.y + 0.5f);
        u.z = (unsigned char)(v.z + 0.5f);
        u.w = (unsigned char)(v.w + 0.5f);
        ((uchar4*)(sib8 + (size_t)i * N))[t] = u;
    }

    // (b) ordered stream compaction over 4 chunks of 256 columns
    __shared__ int woff[4];
    __shared__ int base;
    if (t == 0) base = 0;
    const float* arow = A + (size_t)i * N;
    for (int c = 0; c < 4; ++c) {
        __syncthreads();
        const int j = c * 256 + t;
        const float a = arow[j];
        const unsigned long long m = __ballot(a != 0.0f);
        if (lane == 0) woff[wave] = __popcll(m);
        __syncthreads();
        int off = base;
        for (int w = 0; w < wave; ++w) off += woff[w];
        const int pos = off + __popcll(m & ((1ULL << lane) - 1ULL));
        if (a != 0.0f && pos < KMAX) nbrg[(size_t)i * KMAX + pos] = (unsigned short)j;
        __syncthreads();
        if (t == 0) base += woff[0] + woff[1] + woff[2] + woff[3];
    }
    __syncthreads();
    if (t == 0) cntg[i] = base < KMAX ? base : KMAX;
}

// ---------------------------------------------------------------------------
// wf[i,f] = b2[f] + sum_k nf[i,k]*W2[k,f]; 2 waves per row (k split in half).
// ---------------------------------------------------------------------------
__global__ __launch_bounds__(256) void wf2_kernel(
    const float* __restrict__ nf, const float* __restrict__ W2,
    const float* __restrict__ b2, float* __restrict__ wf)
{
    __shared__ float red[4 * D_OUT];
    const int t = threadIdx.x, lane = t & 63, wave = t >> 6;
    const int row = blockIdx.x * 2 + (wave >> 1);
    const int half = wave & 1;
    const float4* nf4 = (const float4*)(nf + (size_t)row * F_IN);
    float acc = half ? 0.0f : b2[lane];
    #pragma unroll 8
    for (int kk = half * 32; kk < half * 32 + 32; ++kk) {
        const float4 v = nf4[kk];
        const float* w = W2 + kk * 4 * D_OUT + lane;
        acc += v.x * w[0] + v.y * w[D_OUT] + v.z * w[2 * D_OUT] + v.w * w[3 * D_OUT];
    }
    red[wave * D_OUT + lane] = acc;
    __syncthreads();
    if (t < 128) {
        const int rr = t >> 6, f = t & 63;
        wf[(size_t)(blockIdx.x * 2 + rr) * D_OUT + f] =
            red[(rr * 2) * D_OUT + f] + red[(rr * 2 + 1) * D_OUT + f];
    }
}

// ---------------------------------------------------------------------------
// out[i,f] = 2 * sum_{b<j in nbr(i)} sib[b,j]*wf[b,f]*wf[j,f] / nc[i]^2
// 1024 threads/block, one block per node.
// sib submatrix stored TRANSPOSED+packed: sib_sT[j*SROW + bi] (u8), upper
// triangle (bi<j) only, rest zero. Pair loop: wave owns bi-tiles of 4 rows
// (wb[0..3] register tile, amortized), lane=(f4, p) with p parallelizing 4
// j's; per j-step LDS = 1 uchar4 + 1 float4 for 16 pair-terms x 4 features;
// FMA factored as u = sum_r s_r*wb_r; acc += u o wj.
// ---------------------------------------------------------------------------
__global__ __launch_bounds__(1024, 8) void pair2_kernel(
    const unsigned char* __restrict__ sib8, const unsigned short* __restrict__ nbrg,
    const int* __restrict__ cntg, const float* __restrict__ nc,
    const float* __restrict__ wf, float* __restrict__ out)
{
    __shared__ float          wf_s[(KMAX + 4) * D_OUT];   // 33 KB (+4 pad rows)
    __shared__ unsigned char  sib_sT[KMAX * SROW];        // 16.5 KB
    __shared__ unsigned short nbr[KMAX];
    __shared__ float          red[16 * D_OUT];            // 4 KB

    const int i = blockIdx.x, t = threadIdx.x;
    const int wave = t >> 6, lane = t & 63;
    int K = cntg[i]; if (K > 124) K = 124;   // actual max ~93; keeps j=j0+p in-bounds

    // clear sib_sT (16.9 KB as int4) -> lower triangle & pads read as 0
    for (int idx = t; idx < (KMAX * SROW) / 16; idx += 1024)
        ((int4*)sib_sT)[idx] = make_int4(0, 0, 0, 0);
    // zero wf_s pad rows [K, K+4) so s=0 never multiplies garbage
    if (t < 256) wf_s[K * D_OUT + t] = 0.0f;
    if (t < KMAX) nbr[t] = nbrg[(size_t)i * KMAX + t];
    __syncthreads();

    // stage wf rows of neighbors (float4, coalesced per row)
    for (int idx = t; idx < K * (D_OUT / 4); idx += 1024)
        ((float4*)wf_s)[idx] =
            ((const float4*)wf)[(int)nbr[idx >> 4] * (D_OUT / 4) + (idx & 15)];
    // gather upper triangle (bi<j) into transposed LDS; bi-major so
    // consecutive threads read consecutive sorted columns of one sib8 row
    // (L1 line reuse); L2-hot 1 MB source.
    for (int idx = t; idx < K * KMAX; idx += 1024) {
        const int bi = idx >> 7, j = idx & (KMAX - 1);
        if (j > bi && j < K)
            sib_sT[j * SROW + bi] = sib8[(size_t)nbr[bi] * N + nbr[j]];
    }
    __syncthreads();

    // pair loop: wave owns bi-tiles bt = wave, wave+16, ... (rows 4bt..4bt+3)
    const int f4 = (lane & 15) * 4, p = lane >> 4;
    float4 acc = make_float4(0.f, 0.f, 0.f, 0.f);
    for (int bt = wave; bt * 4 < K; bt += 16) {
        const float4 wb0 = *(const float4*)&wf_s[(bt * 4 + 0) * D_OUT + f4];
        const float4 wb1 = *(const float4*)&wf_s[(bt * 4 + 1) * D_OUT + f4];
        const float4 wb2 = *(const float4*)&wf_s[(bt * 4 + 2) * D_OUT + f4];
        const float4 wb3 = *(const float4*)&wf_s[(bt * 4 + 3) * D_OUT + f4];
        const unsigned char* sc = sib_sT + bt * 4;
        for (int j0 = bt * 4; j0 < K; j0 += 4) {
            const int j = j0 + p;                       // <= K+2: zero pad
            const uchar4 s4 = *(const uchar4*)(sc + j * SROW);
            const float4 wj = *(const float4*)&wf_s[j * D_OUT + f4];
            const float sx = (float)s4.x, sy = (float)s4.y,
                        sz = (float)s4.z, sw = (float)s4.w;
            float4 u;
            u.x = sx * wb0.x + sy * wb1.x + sz * wb2.x + sw * wb3.x;
            u.y = sx * wb0.y + sy * wb1.y + sz * wb2.y + sw * wb3.y;
            u.z = sx * wb0.z + sy * wb1.z + sz * wb2.z + sw * wb3.z;
            u.w = sx * wb0.w + sy * wb1.w + sz * wb2.w + sw * wb3.w;
            acc.x += u.x * wj.x;
            acc.y += u.y * wj.y;
            acc.z += u.z * wj.z;
            acc.w += u.w * wj.w;
        }
    }
    // reduce over p (lane bits 4,5) via shuffle butterfly
    #pragma unroll
    for (int m = 16; m <= 32; m += m) {
        acc.x += __shfl_xor(acc.x, m, 64);
        acc.y += __shfl_xor(acc.y, m, 64);
        acc.z += __shfl_xor(acc.z, m, 64);
        acc.w += __shfl_xor(acc.w, m, 64);
    }
    if (p == 0) *(float4*)&red[wave * D_OUT + f4] = acc;
    __syncthreads();

    if (t < D_OUT) {
        float v = 0.f;
        #pragma unroll
        for (int w = 0; w < 16; ++w) v += red[w * D_OUT + t];
        const float c = nc[i];
        out[(size_t)i * D_OUT + t] = 2.0f * v / (c * c);
    }
}

extern "C" void kernel_launch(void* const* d_in, const int* in_sizes, int n_in,
                              void* d_out, int out_size, void* d_ws, size_t ws_size,
                              hipStream_t stream) {
    const float* nf     = (const float*)d_in[0];  // (N, F_IN)
    const float* A      = (const float*)d_in[1];  // (N, N)
    // d_in[2] = mask_father == A[:,None,:], redundant
    const float* nc     = (const float*)d_in[3];  // (N, 1)
    const float* sib    = (const float*)d_in[4];  // mask_hadamard (N, N)
    const float* lin_w  = (const float*)d_in[5];  // (D_IN, F_IN)
    const float* lin_b  = (const float*)d_in[6];  // (D_IN,)
    const float* weight = (const float*)d_in[7];  // (D_IN, D_OUT)
    float*       out    = (float*)d_out;          // (N, D_OUT)

    char* ws = (char*)d_ws;
    float*          wf    = (float*)(ws);                       // 256 KB
    float*          W2    = (float*)(ws + 262144);              // 64 KB
    float*          b2    = (float*)(ws + 327680);              // 1 KB (padded)
    unsigned char*  sib8  = (unsigned char*)(ws + 328704);      // 1 MB
    unsigned short* nbr16 = (unsigned short*)(ws + 1377280);    // 256 KB
    int*            cnt   = (int*)(ws + 1639424);               // 4 KB

    prep_w2_kernel<<<N + 65, 256,  0, stream>>>(A, sib, lin_w, lin_b, weight,
                                                sib8, nbr16, cnt, W2, b2);
    wf2_kernel    <<<N / 2,  256,  0, stream>>>(nf, W2, b2, wf);
    pair2_kernel  <<<N,      1024, 0, stream>>>(sib8, nbr16, cnt, nc, wf, out);
}